// Round 5
// baseline (669.092 us; speedup 1.0000x reference)
//
#include <hip/hip_runtime.h>
#include <hip/hip_bf16.h>

#define NEG 0.01f
#define BN_EPS 1e-5f

typedef __hip_bfloat16 bf16;
typedef __attribute__((ext_vector_type(8))) short short8;
typedef __attribute__((ext_vector_type(16))) float f32x16;

__device__ __forceinline__ float b2f(short s) {
    unsigned u = ((unsigned)(unsigned short)s) << 16;
    float f;
    __builtin_memcpy(&f, &u, 4);
    return f;
}
__device__ __forceinline__ short f2b(float f) {
    union { bf16 b; short s; } t;
    t.b = __float2bfloat16(f);
    return t.s;
}

// ---------------- finalize: sum 32 replicated stat banks -> [mean|rstd] -----
// Replicated banks kill the atomic hot-spot (round 1-3 regression: 2M fp32
// device atomics onto 128 addresses = ~16k serialized memory-side RMWs per
// address = +100us per paired conv dispatch, +20MB phantom WRITE traffic).
__global__ void finalize2_k(const float* __restrict__ sA, const float* __restrict__ sB,
                            float* __restrict__ fA, float* __restrict__ fB,
                            float inv_n) {
    const float* s = blockIdx.x == 0 ? sA : sB;
    float* f = blockIdx.x == 0 ? fA : fB;
    int c = threadIdx.x;  // 64 threads = 64 channels
    float sm = 0.f, sq = 0.f;
    #pragma unroll
    for (int k = 0; k < 32; ++k) {
        sm += s[k * 256 + c];
        sq += s[k * 256 + 64 + c];
    }
    float m = sm * inv_n;
    float v = sq * inv_n - m * m;
    f[c] = m;
    f[64 + c] = rsqrtf(v + BN_EPS);
}

// ---------------- fused elementwise kernels (use finalized mean/rstd) -------

// In-place bnact over TWO tensors (a then b), short8 vectorized.
__global__ __launch_bounds__(256) void bnact2_k(
    bf16* __restrict__ xa, const float* __restrict__ fa,
    bf16* __restrict__ xb, const float* __restrict__ fb, int nvec) {
    int i = blockIdx.x * blockDim.x + threadIdx.x;
    if (i >= 2 * nvec) return;
    bf16* x; const float* f; int j;
    if (i < nvec) { x = xa; f = fa; j = i; }
    else          { x = xb; f = fb; j = i - nvec; }
    const int c0 = (j & 7) << 3;
    short8 v = *reinterpret_cast<const short8*>(x + ((size_t)j << 3));
    short8 o;
    #pragma unroll
    for (int e = 0; e < 8; ++e) {
        float t = (b2f(v[e]) - f[c0 + e]) * f[64 + c0 + e];
        t = t > 0.f ? t : NEG * t;
        o[e] = f2b(t);
    }
    *reinterpret_cast<short8*>(x + ((size_t)j << 3)) = o;
}

// out = bnact(a) + bnact(b), short8 vectorized
__global__ __launch_bounds__(256) void bnadd_k(
    const bf16* __restrict__ a, const float* __restrict__ fa,
    const bf16* __restrict__ b, const float* __restrict__ fb,
    bf16* __restrict__ out, int nvec) {
    int i = blockIdx.x * blockDim.x + threadIdx.x;
    if (i >= nvec) return;
    const int c0 = (i & 7) << 3;
    short8 va = *reinterpret_cast<const short8*>(a + ((size_t)i << 3));
    short8 vb = *reinterpret_cast<const short8*>(b + ((size_t)i << 3));
    short8 o;
    #pragma unroll
    for (int e = 0; e < 8; ++e) {
        float ta = (b2f(va[e]) - fa[c0 + e]) * fa[64 + c0 + e];
        ta = ta > 0.f ? ta : NEG * ta;
        float tb = (b2f(vb[e]) - fb[c0 + e]) * fb[64 + c0 + e];
        tb = tb > 0.f ? tb : NEG * tb;
        o[e] = f2b(ta + tb);
    }
    *reinterpret_cast<short8*>(out + ((size_t)i << 3)) = o;
}

__global__ void cvt_f32_bf16_k(const float* __restrict__ x, bf16* __restrict__ y, int n) {
    int i = blockIdx.x * blockDim.x + threadIdx.x;
    if (i < n) y[i] = __float2bfloat16(x[i]);
}

// ---------------- weight pack (32x32x16 B-fragments, proven layout) ----------
struct PackEnt { const float* src; bf16* dst; int kt; int ns; };
struct PackArgs { PackEnt e[16]; };

__global__ void pack_w_k(PackArgs pa) {
    PackEnt E = pa.e[blockIdx.y];
    int cin = E.ns * 16;
    int total = E.kt * E.ns * 1024;
    for (int i = blockIdx.x * blockDim.x + threadIdx.x; i < total;
         i += gridDim.x * blockDim.x) {
        int j = i & 7, lane = (i >> 3) & 63, c = (i >> 9) & 1;
        int rem = i >> 10;
        int s = rem % E.ns, k = rem / E.ns;
        int krow = s * 16 + ((lane >> 5) << 3) + j;
        int col = c * 32 + (lane & 31);
        E.dst[i] = __float2bfloat16(E.src[((size_t)k * cin + krow) * 64 + col]);
    }
}

// ---------------- fused gather-MFMA sparse conv, 2 jobs per launch -----------
// Inner loop: EXACT round-0 proven body (40 arch VGPR + 32 AGPR).
// Stats epilogue: replicated atomic banks (round-4 win, -100us/dispatch).
// NEW (round 5): bijective XCD-chunked block swizzle (T1/m204). Outputs are
// sorted by voxel linear index, so a tile's gather targets live within a
// ~+/-70-row packed window; a contiguous 1/8 chunk of tiles + halo ~= 4MB
// = one XCD's L2. Default round-robin dispatch makes every XCD's gather
// working set ~25MB -> L2 thrash -> all gathers at L3 latency (~900cyc),
// which is what keeps MfmaUtil at 14%. Chunking makes gathers L2-local.
struct Job {
    const bf16* fin; const int* nbr; const bf16* Wp; bf16* out; float* stat;
    int n_out, n_in;
};
struct Jobs { Job j[2]; int t_split, t_total; };

template <int NS, int K>  // NS = CIN/16, K = taps (multiple of 9)
__global__ __launch_bounds__(256, 6) void mconv3(Jobs jb) {
    const int CIN = NS * 16;
    const int lane = threadIdx.x & 63;
    const int col = lane & 31;
    const int q = lane >> 5;

    // bijective chunked XCD swizzle: XCD x gets a contiguous block chunk
    const int nb = gridDim.x;
    const int qq = nb >> 3, rr = nb & 7;
    const int xcd = blockIdx.x & 7, bi = blockIdx.x >> 3;
    const int sb = (xcd < rr) ? xcd * (qq + 1) + bi
                              : rr * (qq + 1) + (xcd - rr) * qq + bi;

    const int wid = sb * (blockDim.x >> 6) + (threadIdx.x >> 6);
    const int nw = gridDim.x * (blockDim.x >> 6);

    for (int tg = wid; tg < jb.t_total; tg += nw) {
        const int jsel = (tg >= jb.t_split) ? 1 : 0;
        const Job J = jb.j[jsel];
        const int tile = tg - (jsel ? jb.t_split : 0);
        const int rbase = tile << 5;
        const int r = rbase + col;
        const bool rowok = r < J.n_out;

        f32x16 acc0, acc1;
        #pragma unroll
        for (int i = 0; i < 16; ++i) { acc0[i] = 0.f; acc1[i] = 0.f; }

        #pragma unroll
        for (int g = 0; g < K / 9; ++g) {
            // 9 independent coalesced index loads up-front (memory parallelism)
            int idx[9];
            #pragma unroll
            for (int t = 0; t < 9; ++t)
                idx[t] = rowok ? J.nbr[(size_t)(g * 9 + t) * J.n_out + r] : J.n_in;

            #pragma unroll 1
            for (int t = 0; t < 9; ++t) {
                const bool v = idx[t] < J.n_in;
                if (__ballot(v) == 0ull) continue;  // wave-uniform tap skip
                const int k = g * 9 + t;
                const bf16* src = J.fin + (size_t)idx[t] * CIN + q * 8;
                const short8* wp = (const short8*)J.Wp + (size_t)k * (NS * 128) + lane;
                #pragma unroll
                for (int s = 0; s < NS; ++s) {
                    short8 a;
                    if (v) a = *(const short8*)(src + s * 16);
                    else { short8 z = {0,0,0,0,0,0,0,0}; a = z; }
                    short8 b0 = wp[(s * 2 + 0) * 64];
                    short8 b1 = wp[(s * 2 + 1) * 64];
                    acc0 = __builtin_amdgcn_mfma_f32_32x32x16_bf16(a, b0, acc0, 0, 0, 0);
                    acc1 = __builtin_amdgcn_mfma_f32_32x32x16_bf16(a, b1, acc1, 0, 0, 0);
                }
            }
        }

        // epilogue: store bf16 + fused per-channel sum/sumsq (fp32 accuracy)
        float s0 = 0.f, q0 = 0.f, s1 = 0.f, q1 = 0.f;
        #pragma unroll
        for (int i = 0; i < 16; ++i) {
            int row = (i & 3) + 8 * (i >> 2) + 4 * q;
            int gr = rbase + row;
            if (gr < J.n_out) {
                float v0 = acc0[i], v1 = acc1[i];
                J.out[(size_t)gr * 64 + col] = __float2bfloat16(v0);
                J.out[(size_t)gr * 64 + 32 + col] = __float2bfloat16(v1);
                s0 += v0; q0 += v0 * v0;
                s1 += v1; q1 += v1 * v1;
            }
        }
        if (J.stat != nullptr) {
            s0 += __shfl_xor(s0, 32); q0 += __shfl_xor(q0, 32);
            s1 += __shfl_xor(s1, 32); q1 += __shfl_xor(q1, 32);
            // replica bank per wave; halves split the 64 channels
            float* st = J.stat + ((wid & 31) << 8);
            if (q == 0) {
                atomicAdd(&st[col], s0);        // ch col, sum
                atomicAdd(&st[64 + col], q0);   // ch col, sumsq
            } else {
                atomicAdd(&st[32 + col], s1);       // ch 32+col, sum
                atomicAdd(&st[96 + col], q1);       // ch 32+col, sumsq
            }
        }
    }
}

// ---------------- fused down-projection ----------------
__global__ __launch_bounds__(256, 6) void down_k(
    const bf16* __restrict__ x1, const bf16* __restrict__ x2,
    const bf16* __restrict__ x3, const bf16* __restrict__ W1,
    const bf16* __restrict__ W2, const bf16* __restrict__ W3,
    float* __restrict__ out, int m) {
    const int lane = threadIdx.x & 63;
    const int col = lane & 31;
    const int q = lane >> 5;
    const int wid = blockIdx.x * (blockDim.x >> 6) + (threadIdx.x >> 6);
    const int nw = gridDim.x * (blockDim.x >> 6);
    const int ntiles = (m + 31) >> 5;

    for (int tile = wid; tile < ntiles; tile += nw) {
        const int rbase = tile << 5;
        const int r = rbase + col;
        const bool rowok = r < m;

        f32x16 acc0, acc1;
        #pragma unroll
        for (int i = 0; i < 16; ++i) { acc0[i] = 0.f; acc1[i] = 0.f; }

        const bf16* xs[3] = {x1, x2, x3};
        const bf16* ws[3] = {W1, W2, W3};
        #pragma unroll 1
        for (int t = 0; t < 3; ++t) {
            const bf16* src = xs[t] + (size_t)r * 64 + q * 8;
            const short8* wp = (const short8*)ws[t] + lane;
            #pragma unroll
            for (int s = 0; s < 4; ++s) {
                short8 a;
                if (rowok) a = *(const short8*)(src + s * 16);
                else { short8 z = {0,0,0,0,0,0,0,0}; a = z; }
                short8 b0 = wp[(s * 2 + 0) * 64];
                short8 b1 = wp[(s * 2 + 1) * 64];
                acc0 = __builtin_amdgcn_mfma_f32_32x32x16_bf16(a, b0, acc0, 0, 0, 0);
                acc1 = __builtin_amdgcn_mfma_f32_32x32x16_bf16(a, b1, acc1, 0, 0, 0);
            }
        }
        #pragma unroll
        for (int i = 0; i < 16; ++i) {
            int row = (i & 3) + 8 * (i >> 2) + 4 * q;
            int gr = rbase + row;
            if (gr < m) {
                out[(size_t)gr * 64 + col] = acc0[i];
                out[(size_t)gr * 64 + 32 + col] = acc1[i];
            }
        }
    }
}

// ---------------- host ----------------

extern "C" void kernel_launch(void* const* d_in, const int* in_sizes, int n_in_,
                              void* d_out, int out_size, void* d_ws,
                              size_t ws_size, hipStream_t stream) {
    const float* feats = (const float*)d_in[0];
    const float* Wsrc[16] = {
        (const float*)d_in[1], (const float*)d_in[2],
        (const float*)d_in[3], (const float*)d_in[4],
        (const float*)d_in[5],
        (const float*)d_in[6], (const float*)d_in[7],
        (const float*)d_in[8], (const float*)d_in[9],
        (const float*)d_in[10], (const float*)d_in[11],
        (const float*)d_in[12], (const float*)d_in[13],
        (const float*)d_in[14],
        (const float*)d_in[14] + 64 * 64,
        (const float*)d_in[14] + 128 * 64,
    };
    const int kts[16] = {9,9,9,9, 27, 9,9,9,9, 9,9,9,9, 1,1,1};
    const int nss[16] = {2,4,2,4,  4, 4,4,4,4, 4,4,4,4, 4,4,4};

    const int* nA1 = (const int*)d_in[15];
    const int* nB1 = (const int*)d_in[16];
    const int* pnbr = (const int*)d_in[17];
    const int* nA2 = (const int*)d_in[18];
    const int* nB2 = (const int*)d_in[19];
    const int* nA3 = (const int*)d_in[20];
    const int* nB3 = (const int*)d_in[21];

    const int N = in_sizes[0] / 32;
    const int M = in_sizes[17] / 27;
    const size_t MX = (size_t)(N > M ? N : M);

    // ---- workspace ----
    bf16* A = (bf16*)d_ws;
    bf16* B = A + MX * 64;
    bf16* C = B + MX * 64;
    bf16* D = C + MX * 64;   // X1
    bf16* E = D + MX * 64;   // X2
    bf16* FB = E + MX * 64;  // feats bf16, N x 32
    bf16* WP = FB + (size_t)N * 32;
    bf16* G = (bf16*)d_out;  // bf16 scratch inside out (consumed before down_k)
    bf16* Wp[16];
    {
        size_t off = 0;
        for (int i = 0; i < 16; ++i) {
            Wp[i] = WP + off;
            off += (size_t)kts[i] * nss[i] * 1024;
        }
    }
    size_t wp_total = 0;
    for (int i = 0; i < 16; ++i) wp_total += (size_t)kts[i] * nss[i] * 1024;
    // 12 replicated stat slots (32 banks x 256 floats) + 12 finalized slots
    float* ST = (float*)(WP + wp_total + (wp_total & 1));
    float* FS = ST + (size_t)12 * 32 * 256;
    float* out = (float*)d_out;
    auto S = [&](int i) { return ST + (size_t)i * 32 * 256; };
    auto F = [&](int i) { return FS + (size_t)i * 128; };

    // ---- prep ----
    hipMemsetAsync(ST, 0, (size_t)12 * 32 * 256 * sizeof(float), stream);
    {
        PackArgs pa;
        for (int i = 0; i < 16; ++i) pa.e[i] = {Wsrc[i], Wp[i], kts[i], nss[i]};
        pack_w_k<<<dim3(64, 16), 256, 0, stream>>>(pa);
    }
    cvt_f32_bf16_k<<<(N * 32 + 255) / 256, 256, 0, stream>>>(feats, FB, N * 32);

    const float invN = 1.f / (float)N, invM = 1.f / (float)M;
    const int nvN = N * 8, nvM = M * 8;  // short8 vectors per tensor

    auto mkjob = [](const bf16* fin, const int* nbr, const bf16* w, bf16* o,
                    float* st, int no, int ni) {
        Job j; j.fin = fin; j.nbr = nbr; j.Wp = w; j.out = o; j.stat = st;
        j.n_out = no; j.n_in = ni; return j;
    };
    auto pair = [&](void (*kp)(Jobs), Job a, Job b) {
        Jobs jb; jb.j[0] = a; jb.j[1] = b;
        int ta = (a.n_out + 31) >> 5, tb = (b.n_out + 31) >> 5;
        jb.t_split = ta; jb.t_total = ta + tb;
        int blocks = (jb.t_total + 3) >> 2;
        hipLaunchKernelGGL(kp, dim3(blocks), dim3(256), 0, stream, jb);
    };
    auto single = [&](void (*kp)(Jobs), Job a) {
        Jobs jb; jb.j[0] = a; jb.j[1] = a;
        int ta = (a.n_out + 31) >> 5;
        jb.t_split = ta; jb.t_total = ta;
        int blocks = (ta + 3) >> 2;
        hipLaunchKernelGGL(kp, dim3(blocks), dim3(256), 0, stream, jb);
    };

    // ---- block 1 @ N, C 32->64 ----
    pair(mconv3<2, 9>,
         mkjob(FB, nA1, Wp[0], A, S(0), N, N),
         mkjob(FB, nB1, Wp[2], B, S(2), N, N));
    finalize2_k<<<2, 64, 0, stream>>>(S(0), S(2), F(0), F(2), invN);
    bnact2_k<<<(2 * nvN + 255) / 256, 256, 0, stream>>>(A, F(0), B, F(2), nvN);
    pair(mconv3<4, 9>,
         mkjob(A, nB1, Wp[1], C, S(1), N, N),
         mkjob(B, nA1, Wp[3], E, S(3), N, N));
    finalize2_k<<<2, 64, 0, stream>>>(S(1), S(3), F(1), F(3), invN);
    bnadd_k<<<(nvN + 255) / 256, 256, 0, stream>>>(C, F(1), E, F(3), B, nvN);
    // XP = B (N x 64)

    // ---- strided pool, K=27: B (N,64) -> D (M,64) = X1 ----
    single(mconv3<4, 27>, mkjob(B, pnbr, Wp[4], D, nullptr, M, N));

    // ---- block 2 @ M (fin = D) ----
    pair(mconv3<4, 9>,
         mkjob(D, nA2, Wp[5], A, S(4), M, M),
         mkjob(D, nB2, Wp[7], B, S(6), M, M));
    finalize2_k<<<2, 64, 0, stream>>>(S(4), S(6), F(4), F(6), invM);
    bnact2_k<<<(2 * nvM + 255) / 256, 256, 0, stream>>>(A, F(4), B, F(6), nvM);
    pair(mconv3<4, 9>,
         mkjob(A, nB2, Wp[6], C, S(5), M, M),
         mkjob(B, nA2, Wp[8], E, S(7), M, M));
    finalize2_k<<<2, 64, 0, stream>>>(S(5), S(7), F(5), F(7), invM);
    bnadd_k<<<(nvM + 255) / 256, 256, 0, stream>>>(C, F(5), E, F(7), E, nvM);
    // X2 = E

    // ---- block 3 @ M (fin = E) ----
    pair(mconv3<4, 9>,
         mkjob(E, nA3, Wp[9], A, S(8), M, M),
         mkjob(E, nB3, Wp[11], B, S(10), M, M));
    finalize2_k<<<2, 64, 0, stream>>>(S(8), S(10), F(8), F(10), invM);
    bnact2_k<<<(2 * nvM + 255) / 256, 256, 0, stream>>>(A, F(8), B, F(10), nvM);
    pair(mconv3<4, 9>,
         mkjob(A, nB3, Wp[10], C, S(9), M, M),
         mkjob(B, nA3, Wp[12], G, S(11), M, M));
    finalize2_k<<<2, 64, 0, stream>>>(S(9), S(11), F(9), F(11), invM);
    bnadd_k<<<(nvM + 255) / 256, 256, 0, stream>>>(C, F(9), G, F(11), B, nvM);
    // X3 = B  (G scratch consumed)

    // ---- fused down: out = X1@W1 + X2@W2 + X3@W3 ----
    {
        int blocks = (((M + 31) >> 5) + 3) >> 2;
        down_k<<<blocks, 256, 0, stream>>>(D, E, B, Wp[13], Wp[14], Wp[15], out, M);
    }
}

// Round 6
// 604.915 us; speedup vs baseline: 1.1061x; 1.1061x over previous
//
#include <hip/hip_runtime.h>
#include <hip/hip_bf16.h>

#define NEG 0.01f
#define BN_EPS 1e-5f

typedef __hip_bfloat16 bf16;
typedef __attribute__((ext_vector_type(8))) short short8;
typedef __attribute__((ext_vector_type(16))) float f32x16;

__device__ __forceinline__ float b2f(short s) {
    unsigned u = ((unsigned)(unsigned short)s) << 16;
    float f;
    __builtin_memcpy(&f, &u, 4);
    return f;
}
__device__ __forceinline__ short f2b(float f) {
    union { bf16 b; short s; } t;
    t.b = __float2bfloat16(f);
    return t.s;
}

// ---------------- finalize: sum 32 replicated stat banks -> [mean|rstd] -----
__global__ void finalize2_k(const float* __restrict__ sA, const float* __restrict__ sB,
                            float* __restrict__ fA, float* __restrict__ fB,
                            float inv_n) {
    const float* s = blockIdx.x == 0 ? sA : sB;
    float* f = blockIdx.x == 0 ? fA : fB;
    int c = threadIdx.x;  // 64 threads = 64 channels
    float sm = 0.f, sq = 0.f;
    #pragma unroll
    for (int k = 0; k < 32; ++k) {
        sm += s[k * 256 + c];
        sq += s[k * 256 + 64 + c];
    }
    float m = sm * inv_n;
    float v = sq * inv_n - m * m;
    f[c] = m;
    f[64 + c] = rsqrtf(v + BN_EPS);
}

// ---------------- fused elementwise kernels (use finalized mean/rstd) -------

__global__ __launch_bounds__(256) void bnact2_k(
    bf16* __restrict__ xa, const float* __restrict__ fa,
    bf16* __restrict__ xb, const float* __restrict__ fb, int nvec) {
    int i = blockIdx.x * blockDim.x + threadIdx.x;
    if (i >= 2 * nvec) return;
    bf16* x; const float* f; int j;
    if (i < nvec) { x = xa; f = fa; j = i; }
    else          { x = xb; f = fb; j = i - nvec; }
    const int c0 = (j & 7) << 3;
    short8 v = *reinterpret_cast<const short8*>(x + ((size_t)j << 3));
    short8 o;
    #pragma unroll
    for (int e = 0; e < 8; ++e) {
        float t = (b2f(v[e]) - f[c0 + e]) * f[64 + c0 + e];
        t = t > 0.f ? t : NEG * t;
        o[e] = f2b(t);
    }
    *reinterpret_cast<short8*>(x + ((size_t)j << 3)) = o;
}

__global__ __launch_bounds__(256) void bnadd_k(
    const bf16* __restrict__ a, const float* __restrict__ fa,
    const bf16* __restrict__ b, const float* __restrict__ fb,
    bf16* __restrict__ out, int nvec) {
    int i = blockIdx.x * blockDim.x + threadIdx.x;
    if (i >= nvec) return;
    const int c0 = (i & 7) << 3;
    short8 va = *reinterpret_cast<const short8*>(a + ((size_t)i << 3));
    short8 vb = *reinterpret_cast<const short8*>(b + ((size_t)i << 3));
    short8 o;
    #pragma unroll
    for (int e = 0; e < 8; ++e) {
        float ta = (b2f(va[e]) - fa[c0 + e]) * fa[64 + c0 + e];
        ta = ta > 0.f ? ta : NEG * ta;
        float tb = (b2f(vb[e]) - fb[c0 + e]) * fb[64 + c0 + e];
        tb = tb > 0.f ? tb : NEG * tb;
        o[e] = f2b(ta + tb);
    }
    *reinterpret_cast<short8*>(out + ((size_t)i << 3)) = o;
}

__global__ void cvt_f32_bf16_k(const float* __restrict__ x, bf16* __restrict__ y, int n) {
    int i = blockIdx.x * blockDim.x + threadIdx.x;
    if (i < n) y[i] = __float2bfloat16(x[i]);
}

// ---------------- weight pack (32x32x16 B-fragments, proven layout) ----------
struct PackEnt { const float* src; bf16* dst; int kt; int ns; };
struct PackArgs { PackEnt e[16]; };

__global__ void pack_w_k(PackArgs pa) {
    PackEnt E = pa.e[blockIdx.y];
    int cin = E.ns * 16;
    int total = E.kt * E.ns * 1024;
    for (int i = blockIdx.x * blockDim.x + threadIdx.x; i < total;
         i += gridDim.x * blockDim.x) {
        int j = i & 7, lane = (i >> 3) & 63, c = (i >> 9) & 1;
        int rem = i >> 10;
        int s = rem % E.ns, k = rem / E.ns;
        int krow = s * 16 + ((lane >> 5) << 3) + j;
        int col = c * 32 + (lane & 31);
        E.dst[i] = __float2bfloat16(E.src[((size_t)k * cin + krow) * 64 + col]);
    }
}

struct Job {
    const bf16* fin; const int* nbr; const bf16* Wp; bf16* out; float* stat;
    int n_out, n_in;
};
struct Jobs { Job j[2]; int t_split, t_total; };   // for mconv3 (pool)
struct Jobs4 { Job j[2]; int b_split; };           // for mconv4 (block->job)

// ---------------- mconv4: LDS-cached weights + cross-tap A double-buffer ----
// Round-5 diagnosis: convs are TCP-transaction-service bound (~0.74 req/cyc/CU)
// and half the stream is per-tap global B-loads re-reading a 72KB weight set
// (~660MB/dispatch). Staging B in LDS once per block (a) halves the vmem
// transaction stream, (b) makes the round-2 A-prefetch finally work: with no
// global B-loads per tap, MFMA(t) waits at vmcnt(gather t+1 outstanding)
// instead of draining everything (ordered-vmcnt trap that sank round 2).
// One job per block so a single 72KB weight set is staged; grid=512 (2
// blocks/CU by LDS), 8 waves/block -> 16 waves/CU ~= round-5's measured 13.
template <int NS, int K>  // K must be odd (9); NS = CIN/16
__global__ __launch_bounds__(512, 4) void mconv4(Jobs4 jb) {
    __shared__ short8 WL[K * NS * 128];  // K*NS*2KB (72KB @ NS=4,K=9)
    const int CIN = NS * 16;
    const int tid = threadIdx.x;
    const int lane = tid & 63;
    const int col = lane & 31;
    const int q = lane >> 5;
    const int widl = tid >> 6;           // 0..7
    const int nwl = blockDim.x >> 6;     // 8

    // bijective chunked XCD swizzle (keep: -18% FETCH, free)
    const int nb = gridDim.x;
    const int qq = nb >> 3, rr = nb & 7;
    const int xcd = blockIdx.x & 7, bi = blockIdx.x >> 3;
    const int sb = (xcd < rr) ? xcd * (qq + 1) + bi
                              : rr * (qq + 1) + (xcd - rr) * qq + bi;

    // block -> job assignment
    const int jsel = (sb >= jb.b_split) ? 1 : 0;
    const Job J = jb.j[jsel];
    const int lb = jsel ? sb - jb.b_split : sb;
    const int nbj = jsel ? nb - jb.b_split : jb.b_split;
    const int ntiles = (J.n_out + 31) >> 5;

    // stage this job's packed weights; global layout == LDS layout (linear)
    {
        const short8* wsrc = (const short8*)J.Wp;
        for (int i = tid; i < K * NS * 128; i += blockDim.x) WL[i] = wsrc[i];
    }
    __syncthreads();

    const int wid = lb * nwl + widl;
    const int nw = nbj * nwl;

    for (int tile = wid; tile < ntiles; tile += nw) {
        const int rbase = tile << 5;
        const int r = rbase + col;
        const bool rowok = r < J.n_out;

        f32x16 acc0, acc1;
        #pragma unroll
        for (int i = 0; i < 16; ++i) { acc0[i] = 0.f; acc1[i] = 0.f; }

        int idx[K];
        #pragma unroll
        for (int t = 0; t < K; ++t)
            idx[t] = rowok ? J.nbr[(size_t)t * J.n_out + r] : J.n_in;

        // gather one tap's A-fragments into a register buffer (predicated)
        auto loadA = [&](int id, short8 (&dst)[NS]) {
            const bool v = id < J.n_in;
            const bf16* src = J.fin + (size_t)id * CIN + q * 8;
            #pragma unroll
            for (int s = 0; s < NS; ++s) {
                short8 z = {0, 0, 0, 0, 0, 0, 0, 0};
                dst[s] = z;
                if (v) dst[s] = *(const short8*)(src + s * 16);
            }
        };
        // consume one tap: B from LDS + MFMA, wave-uniform skip
        auto dotap = [&](int k, int id, short8 (&a)[NS]) {
            if (__ballot(id < J.n_in) == 0ull) return;
            #pragma unroll
            for (int s = 0; s < NS; ++s) {
                short8 b0 = WL[((k * NS + s) * 2 + 0) * 64 + lane];
                short8 b1 = WL[((k * NS + s) * 2 + 1) * 64 + lane];
                acc0 = __builtin_amdgcn_mfma_f32_32x32x16_bf16(a[s], b0, acc0, 0, 0, 0);
                acc1 = __builtin_amdgcn_mfma_f32_32x32x16_bf16(a[s], b1, acc1, 0, 0, 0);
            }
        };

        short8 A0[NS], A1[NS];
        loadA(idx[0], A0);
        #pragma unroll 1
        for (int t = 0; t + 2 <= K; t += 2) {
            loadA(idx[t + 1], A1);          // prefetch next while doing cur
            dotap(t, idx[t], A0);
            if (t + 2 < K) loadA(idx[t + 2], A0);
            dotap(t + 1, idx[t + 1], A1);
        }
        dotap(K - 1, idx[K - 1], A0);       // K odd

        // epilogue: store bf16 + fused per-channel sum/sumsq
        float s0 = 0.f, q0 = 0.f, s1 = 0.f, q1 = 0.f;
        #pragma unroll
        for (int i = 0; i < 16; ++i) {
            int row = (i & 3) + 8 * (i >> 2) + 4 * q;
            int gr = rbase + row;
            if (gr < J.n_out) {
                float v0 = acc0[i], v1 = acc1[i];
                J.out[(size_t)gr * 64 + col] = __float2bfloat16(v0);
                J.out[(size_t)gr * 64 + 32 + col] = __float2bfloat16(v1);
                s0 += v0; q0 += v0 * v0;
                s1 += v1; q1 += v1 * v1;
            }
        }
        if (J.stat != nullptr) {
            s0 += __shfl_xor(s0, 32); q0 += __shfl_xor(q0, 32);
            s1 += __shfl_xor(s1, 32); q1 += __shfl_xor(q1, 32);
            float* st = J.stat + (((sb << 3) + widl) & 31) * 256;
            if (q == 0) {
                atomicAdd(&st[col], s0);
                atomicAdd(&st[64 + col], q0);
            } else {
                atomicAdd(&st[32 + col], s1);
                atomicAdd(&st[96 + col], q1);
            }
        }
    }
}

// ---------------- mconv3: pool path (K=27, weights too big for LDS) ---------
template <int NS, int K>
__global__ __launch_bounds__(256, 6) void mconv3(Jobs jb) {
    const int CIN = NS * 16;
    const int lane = threadIdx.x & 63;
    const int col = lane & 31;
    const int q = lane >> 5;

    const int nb = gridDim.x;
    const int qq = nb >> 3, rr = nb & 7;
    const int xcd = blockIdx.x & 7, bi = blockIdx.x >> 3;
    const int sb = (xcd < rr) ? xcd * (qq + 1) + bi
                              : rr * (qq + 1) + (xcd - rr) * qq + bi;

    const int wid = sb * (blockDim.x >> 6) + (threadIdx.x >> 6);
    const int nw = gridDim.x * (blockDim.x >> 6);

    for (int tg = wid; tg < jb.t_total; tg += nw) {
        const int jsel = (tg >= jb.t_split) ? 1 : 0;
        const Job J = jb.j[jsel];
        const int tile = tg - (jsel ? jb.t_split : 0);
        const int rbase = tile << 5;
        const int r = rbase + col;
        const bool rowok = r < J.n_out;

        f32x16 acc0, acc1;
        #pragma unroll
        for (int i = 0; i < 16; ++i) { acc0[i] = 0.f; acc1[i] = 0.f; }

        #pragma unroll
        for (int g = 0; g < K / 9; ++g) {
            int idx[9];
            #pragma unroll
            for (int t = 0; t < 9; ++t)
                idx[t] = rowok ? J.nbr[(size_t)(g * 9 + t) * J.n_out + r] : J.n_in;

            #pragma unroll 1
            for (int t = 0; t < 9; ++t) {
                const bool v = idx[t] < J.n_in;
                if (__ballot(v) == 0ull) continue;
                const int k = g * 9 + t;
                const bf16* src = J.fin + (size_t)idx[t] * CIN + q * 8;
                const short8* wp = (const short8*)J.Wp + (size_t)k * (NS * 128) + lane;
                #pragma unroll
                for (int s = 0; s < NS; ++s) {
                    short8 a;
                    if (v) a = *(const short8*)(src + s * 16);
                    else { short8 z = {0,0,0,0,0,0,0,0}; a = z; }
                    short8 b0 = wp[(s * 2 + 0) * 64];
                    short8 b1 = wp[(s * 2 + 1) * 64];
                    acc0 = __builtin_amdgcn_mfma_f32_32x32x16_bf16(a, b0, acc0, 0, 0, 0);
                    acc1 = __builtin_amdgcn_mfma_f32_32x32x16_bf16(a, b1, acc1, 0, 0, 0);
                }
            }
        }

        #pragma unroll
        for (int i = 0; i < 16; ++i) {
            int row = (i & 3) + 8 * (i >> 2) + 4 * q;
            int gr = rbase + row;
            if (gr < J.n_out) {
                J.out[(size_t)gr * 64 + col] = __float2bfloat16(acc0[i]);
                J.out[(size_t)gr * 64 + 32 + col] = __float2bfloat16(acc1[i]);
            }
        }
    }
}

// ---------------- fused down-projection ----------------
__global__ __launch_bounds__(256, 6) void down_k(
    const bf16* __restrict__ x1, const bf16* __restrict__ x2,
    const bf16* __restrict__ x3, const bf16* __restrict__ W1,
    const bf16* __restrict__ W2, const bf16* __restrict__ W3,
    float* __restrict__ out, int m) {
    const int lane = threadIdx.x & 63;
    const int col = lane & 31;
    const int q = lane >> 5;
    const int wid = blockIdx.x * (blockDim.x >> 6) + (threadIdx.x >> 6);
    const int nw = gridDim.x * (blockDim.x >> 6);
    const int ntiles = (m + 31) >> 5;

    for (int tile = wid; tile < ntiles; tile += nw) {
        const int rbase = tile << 5;
        const int r = rbase + col;
        const bool rowok = r < m;

        f32x16 acc0, acc1;
        #pragma unroll
        for (int i = 0; i < 16; ++i) { acc0[i] = 0.f; acc1[i] = 0.f; }

        const bf16* xs[3] = {x1, x2, x3};
        const bf16* ws[3] = {W1, W2, W3};
        #pragma unroll 1
        for (int t = 0; t < 3; ++t) {
            const bf16* src = xs[t] + (size_t)r * 64 + q * 8;
            const short8* wp = (const short8*)ws[t] + lane;
            #pragma unroll
            for (int s = 0; s < 4; ++s) {
                short8 a;
                if (rowok) a = *(const short8*)(src + s * 16);
                else { short8 z = {0,0,0,0,0,0,0,0}; a = z; }
                short8 b0 = wp[(s * 2 + 0) * 64];
                short8 b1 = wp[(s * 2 + 1) * 64];
                acc0 = __builtin_amdgcn_mfma_f32_32x32x16_bf16(a, b0, acc0, 0, 0, 0);
                acc1 = __builtin_amdgcn_mfma_f32_32x32x16_bf16(a, b1, acc1, 0, 0, 0);
            }
        }
        #pragma unroll
        for (int i = 0; i < 16; ++i) {
            int row = (i & 3) + 8 * (i >> 2) + 4 * q;
            int gr = rbase + row;
            if (gr < m) {
                out[(size_t)gr * 64 + col] = acc0[i];
                out[(size_t)gr * 64 + 32 + col] = acc1[i];
            }
        }
    }
}

// ---------------- host ----------------

extern "C" void kernel_launch(void* const* d_in, const int* in_sizes, int n_in_,
                              void* d_out, int out_size, void* d_ws,
                              size_t ws_size, hipStream_t stream) {
    const float* feats = (const float*)d_in[0];
    const float* Wsrc[16] = {
        (const float*)d_in[1], (const float*)d_in[2],
        (const float*)d_in[3], (const float*)d_in[4],
        (const float*)d_in[5],
        (const float*)d_in[6], (const float*)d_in[7],
        (const float*)d_in[8], (const float*)d_in[9],
        (const float*)d_in[10], (const float*)d_in[11],
        (const float*)d_in[12], (const float*)d_in[13],
        (const float*)d_in[14],
        (const float*)d_in[14] + 64 * 64,
        (const float*)d_in[14] + 128 * 64,
    };
    const int kts[16] = {9,9,9,9, 27, 9,9,9,9, 9,9,9,9, 1,1,1};
    const int nss[16] = {2,4,2,4,  4, 4,4,4,4, 4,4,4,4, 4,4,4};

    const int* nA1 = (const int*)d_in[15];
    const int* nB1 = (const int*)d_in[16];
    const int* pnbr = (const int*)d_in[17];
    const int* nA2 = (const int*)d_in[18];
    const int* nB2 = (const int*)d_in[19];
    const int* nA3 = (const int*)d_in[20];
    const int* nB3 = (const int*)d_in[21];

    const int N = in_sizes[0] / 32;
    const int M = in_sizes[17] / 27;
    const size_t MX = (size_t)(N > M ? N : M);

    // ---- workspace ----
    bf16* A = (bf16*)d_ws;
    bf16* B = A + MX * 64;
    bf16* C = B + MX * 64;
    bf16* D = C + MX * 64;   // X1
    bf16* E = D + MX * 64;   // X2
    bf16* FB = E + MX * 64;  // feats bf16, N x 32
    bf16* WP = FB + (size_t)N * 32;
    bf16* G = (bf16*)d_out;  // bf16 scratch inside out (consumed before down_k)
    bf16* Wp[16];
    {
        size_t off = 0;
        for (int i = 0; i < 16; ++i) {
            Wp[i] = WP + off;
            off += (size_t)kts[i] * nss[i] * 1024;
        }
    }
    size_t wp_total = 0;
    for (int i = 0; i < 16; ++i) wp_total += (size_t)kts[i] * nss[i] * 1024;
    // 12 replicated stat slots (32 banks x 256 floats) + 12 finalized slots
    float* ST = (float*)(WP + wp_total + (wp_total & 1));
    float* FS = ST + (size_t)12 * 32 * 256;
    float* out = (float*)d_out;
    auto S = [&](int i) { return ST + (size_t)i * 32 * 256; };
    auto F = [&](int i) { return FS + (size_t)i * 128; };

    // ---- prep ----
    hipMemsetAsync(ST, 0, (size_t)12 * 32 * 256 * sizeof(float), stream);
    {
        PackArgs pa;
        for (int i = 0; i < 16; ++i) pa.e[i] = {Wsrc[i], Wp[i], kts[i], nss[i]};
        pack_w_k<<<dim3(64, 16), 256, 0, stream>>>(pa);
    }
    cvt_f32_bf16_k<<<(N * 32 + 255) / 256, 256, 0, stream>>>(feats, FB, N * 32);

    const float invN = 1.f / (float)N, invM = 1.f / (float)M;
    const int nvN = N * 8, nvM = M * 8;  // short8 vectors per tensor

    auto mkjob = [](const bf16* fin, const int* nbr, const bf16* w, bf16* o,
                    float* st, int no, int ni) {
        Job j; j.fin = fin; j.nbr = nbr; j.Wp = w; j.out = o; j.stat = st;
        j.n_out = no; j.n_in = ni; return j;
    };
    // paired 9-tap convs: one job per block, LDS weights, 512 thr, grid 512
    auto pair4 = [&](void (*kp)(Jobs4), Job a, Job b) {
        Jobs4 jb; jb.j[0] = a; jb.j[1] = b;
        const int nb = 512;
        long ta = (a.n_out + 31) >> 5, tb = (b.n_out + 31) >> 5;
        int bs = (int)((ta * nb + (ta + tb) / 2) / (ta + tb));
        if (bs < 1) bs = 1;
        if (bs > nb - 1) bs = nb - 1;
        jb.b_split = bs;
        hipLaunchKernelGGL(kp, dim3(nb), dim3(512), 0, stream, jb);
    };
    auto single = [&](void (*kp)(Jobs), Job a) {
        Jobs jb; jb.j[0] = a; jb.j[1] = a;
        int ta = (a.n_out + 31) >> 5;
        jb.t_split = ta; jb.t_total = ta;
        int blocks = (ta + 3) >> 2;
        hipLaunchKernelGGL(kp, dim3(blocks), dim3(256), 0, stream, jb);
    };

    // ---- block 1 @ N, C 32->64 ----
    pair4(mconv4<2, 9>,
          mkjob(FB, nA1, Wp[0], A, S(0), N, N),
          mkjob(FB, nB1, Wp[2], B, S(2), N, N));
    finalize2_k<<<2, 64, 0, stream>>>(S(0), S(2), F(0), F(2), invN);
    bnact2_k<<<(2 * nvN + 255) / 256, 256, 0, stream>>>(A, F(0), B, F(2), nvN);
    pair4(mconv4<4, 9>,
          mkjob(A, nB1, Wp[1], C, S(1), N, N),
          mkjob(B, nA1, Wp[3], E, S(3), N, N));
    finalize2_k<<<2, 64, 0, stream>>>(S(1), S(3), F(1), F(3), invN);
    bnadd_k<<<(nvN + 255) / 256, 256, 0, stream>>>(C, F(1), E, F(3), B, nvN);
    // XP = B (N x 64)

    // ---- strided pool, K=27: B (N,64) -> D (M,64) = X1 ----
    single(mconv3<4, 27>, mkjob(B, pnbr, Wp[4], D, nullptr, M, N));

    // ---- block 2 @ M (fin = D) ----
    pair4(mconv4<4, 9>,
          mkjob(D, nA2, Wp[5], A, S(4), M, M),
          mkjob(D, nB2, Wp[7], B, S(6), M, M));
    finalize2_k<<<2, 64, 0, stream>>>(S(4), S(6), F(4), F(6), invM);
    bnact2_k<<<(2 * nvM + 255) / 256, 256, 0, stream>>>(A, F(4), B, F(6), nvM);
    pair4(mconv4<4, 9>,
          mkjob(A, nB2, Wp[6], C, S(5), M, M),
          mkjob(B, nA2, Wp[8], E, S(7), M, M));
    finalize2_k<<<2, 64, 0, stream>>>(S(5), S(7), F(5), F(7), invM);
    bnadd_k<<<(nvM + 255) / 256, 256, 0, stream>>>(C, F(5), E, F(7), E, nvM);
    // X2 = E

    // ---- block 3 @ M (fin = E) ----
    pair4(mconv4<4, 9>,
          mkjob(E, nA3, Wp[9], A, S(8), M, M),
          mkjob(E, nB3, Wp[11], B, S(10), M, M));
    finalize2_k<<<2, 64, 0, stream>>>(S(8), S(10), F(8), F(10), invM);
    bnact2_k<<<(2 * nvM + 255) / 256, 256, 0, stream>>>(A, F(8), B, F(10), nvM);
    pair4(mconv4<4, 9>,
          mkjob(A, nB3, Wp[10], C, S(9), M, M),
          mkjob(B, nA3, Wp[12], G, S(11), M, M));
    finalize2_k<<<2, 64, 0, stream>>>(S(9), S(11), F(9), F(11), invM);
    bnadd_k<<<(nvM + 255) / 256, 256, 0, stream>>>(C, F(9), G, F(11), B, nvM);
    // X3 = B  (G scratch consumed)

    // ---- fused down: out = X1@W1 + X2@W2 + X3@W3 ----
    {
        int blocks = (((M + 31) >> 5) + 3) >> 2;
        down_k<<<blocks, 256, 0, stream>>>(D, E, B, Wp[13], Wp[14], Wp[15], out, M);
    }
}

// Round 7
// 602.587 us; speedup vs baseline: 1.1104x; 1.0039x over previous
//
#include <hip/hip_runtime.h>
#include <hip/hip_bf16.h>

#define NEG 0.01f
#define BN_EPS 1e-5f

typedef __hip_bfloat16 bf16;
typedef __attribute__((ext_vector_type(8))) short short8;
typedef __attribute__((ext_vector_type(16))) float f32x16;

__device__ __forceinline__ float b2f(short s) {
    unsigned u = ((unsigned)(unsigned short)s) << 16;
    float f;
    __builtin_memcpy(&f, &u, 4);
    return f;
}
__device__ __forceinline__ short f2b(float f) {
    union { bf16 b; short s; } t;
    t.b = __float2bfloat16(f);
    return t.s;
}

// ---------------- finalize: sum 32 replicated stat banks -> [mean|rstd] -----
__global__ void finalize2_k(const float* __restrict__ sA, const float* __restrict__ sB,
                            float* __restrict__ fA, float* __restrict__ fB,
                            float inv_n) {
    const float* s = blockIdx.x == 0 ? sA : sB;
    float* f = blockIdx.x == 0 ? fA : fB;
    int c = threadIdx.x;  // 64 threads = 64 channels
    float sm = 0.f, sq = 0.f;
    #pragma unroll
    for (int k = 0; k < 32; ++k) {
        sm += s[k * 256 + c];
        sq += s[k * 256 + 64 + c];
    }
    float m = sm * inv_n;
    float v = sq * inv_n - m * m;
    f[c] = m;
    f[64 + c] = rsqrtf(v + BN_EPS);
}

// ---------------- fused elementwise kernels (use finalized mean/rstd) -------

__global__ __launch_bounds__(256) void bnact2_k(
    bf16* __restrict__ xa, const float* __restrict__ fa,
    bf16* __restrict__ xb, const float* __restrict__ fb, int nvec) {
    int i = blockIdx.x * blockDim.x + threadIdx.x;
    if (i >= 2 * nvec) return;
    bf16* x; const float* f; int j;
    if (i < nvec) { x = xa; f = fa; j = i; }
    else          { x = xb; f = fb; j = i - nvec; }
    const int c0 = (j & 7) << 3;
    short8 v = *reinterpret_cast<const short8*>(x + ((size_t)j << 3));
    short8 o;
    #pragma unroll
    for (int e = 0; e < 8; ++e) {
        float t = (b2f(v[e]) - f[c0 + e]) * f[64 + c0 + e];
        t = t > 0.f ? t : NEG * t;
        o[e] = f2b(t);
    }
    *reinterpret_cast<short8*>(x + ((size_t)j << 3)) = o;
}

__global__ __launch_bounds__(256) void bnadd_k(
    const bf16* __restrict__ a, const float* __restrict__ fa,
    const bf16* __restrict__ b, const float* __restrict__ fb,
    bf16* __restrict__ out, int nvec) {
    int i = blockIdx.x * blockDim.x + threadIdx.x;
    if (i >= nvec) return;
    const int c0 = (i & 7) << 3;
    short8 va = *reinterpret_cast<const short8*>(a + ((size_t)i << 3));
    short8 vb = *reinterpret_cast<const short8*>(b + ((size_t)i << 3));
    short8 o;
    #pragma unroll
    for (int e = 0; e < 8; ++e) {
        float ta = (b2f(va[e]) - fa[c0 + e]) * fa[64 + c0 + e];
        ta = ta > 0.f ? ta : NEG * ta;
        float tb = (b2f(vb[e]) - fb[c0 + e]) * fb[64 + c0 + e];
        tb = tb > 0.f ? tb : NEG * tb;
        o[e] = f2b(ta + tb);
    }
    *reinterpret_cast<short8*>(out + ((size_t)i << 3)) = o;
}

__global__ void cvt_f32_bf16_k(const float* __restrict__ x, bf16* __restrict__ y, int n) {
    int i = blockIdx.x * blockDim.x + threadIdx.x;
    if (i < n) y[i] = __float2bfloat16(x[i]);
}

// ---------------- weight pack (32x32x16 B-fragments, proven layout) ----------
struct PackEnt { const float* src; bf16* dst; int kt; int ns; };
struct PackArgs { PackEnt e[16]; };

__global__ void pack_w_k(PackArgs pa) {
    PackEnt E = pa.e[blockIdx.y];
    int cin = E.ns * 16;
    int total = E.kt * E.ns * 1024;
    for (int i = blockIdx.x * blockDim.x + threadIdx.x; i < total;
         i += gridDim.x * blockDim.x) {
        int j = i & 7, lane = (i >> 3) & 63, c = (i >> 9) & 1;
        int rem = i >> 10;
        int s = rem % E.ns, k = rem / E.ns;
        int krow = s * 16 + ((lane >> 5) << 3) + j;
        int col = c * 32 + (lane & 31);
        E.dst[i] = __float2bfloat16(E.src[((size_t)k * cin + krow) * 64 + col]);
    }
}

struct Job {
    const bf16* fin; const int* nbr; const bf16* Wp; bf16* out; float* stat;
    int n_out, n_in;
};
struct Jobs4 { Job j[2]; int b_split; };           // for mconv4 (block->job)

// ---------------- mconv4: LDS-cached weights + cross-tap A double-buffer ----
// (round-6 win) One job per block, 72KB weight set staged once; A-prefetch
// works because no per-tap global B-loads pollute the vmcnt chain.
template <int NS, int K>  // K must be odd (9); NS = CIN/16
__global__ __launch_bounds__(512, 4) void mconv4(Jobs4 jb) {
    __shared__ short8 WL[K * NS * 128];  // 72KB @ NS=4,K=9
    const int CIN = NS * 16;
    const int tid = threadIdx.x;
    const int lane = tid & 63;
    const int col = lane & 31;
    const int q = lane >> 5;
    const int widl = tid >> 6;           // 0..7
    const int nwl = blockDim.x >> 6;     // 8

    // bijective chunked XCD swizzle
    const int nb = gridDim.x;
    const int qq = nb >> 3, rr = nb & 7;
    const int xcd = blockIdx.x & 7, bi = blockIdx.x >> 3;
    const int sb = (xcd < rr) ? xcd * (qq + 1) + bi
                              : rr * (qq + 1) + (xcd - rr) * qq + bi;

    // block -> job assignment
    const int jsel = (sb >= jb.b_split) ? 1 : 0;
    const Job J = jb.j[jsel];
    const int lb = jsel ? sb - jb.b_split : sb;
    const int nbj = jsel ? nb - jb.b_split : jb.b_split;
    const int ntiles = (J.n_out + 31) >> 5;

    // stage this job's packed weights; global layout == LDS layout (linear)
    {
        const short8* wsrc = (const short8*)J.Wp;
        for (int i = tid; i < K * NS * 128; i += blockDim.x) WL[i] = wsrc[i];
    }
    __syncthreads();

    const int wid = lb * nwl + widl;
    const int nw = nbj * nwl;

    for (int tile = wid; tile < ntiles; tile += nw) {
        const int rbase = tile << 5;
        const int r = rbase + col;
        const bool rowok = r < J.n_out;

        f32x16 acc0, acc1;
        #pragma unroll
        for (int i = 0; i < 16; ++i) { acc0[i] = 0.f; acc1[i] = 0.f; }

        int idx[K];
        #pragma unroll
        for (int t = 0; t < K; ++t)
            idx[t] = rowok ? J.nbr[(size_t)t * J.n_out + r] : J.n_in;

        auto loadA = [&](int id, short8 (&dst)[NS]) {
            const bool v = id < J.n_in;
            const bf16* src = J.fin + (size_t)id * CIN + q * 8;
            #pragma unroll
            for (int s = 0; s < NS; ++s) {
                short8 z = {0, 0, 0, 0, 0, 0, 0, 0};
                dst[s] = z;
                if (v) dst[s] = *(const short8*)(src + s * 16);
            }
        };
        auto dotap = [&](int k, int id, short8 (&a)[NS]) {
            if (__ballot(id < J.n_in) == 0ull) return;
            #pragma unroll
            for (int s = 0; s < NS; ++s) {
                short8 b0 = WL[((k * NS + s) * 2 + 0) * 64 + lane];
                short8 b1 = WL[((k * NS + s) * 2 + 1) * 64 + lane];
                acc0 = __builtin_amdgcn_mfma_f32_32x32x16_bf16(a[s], b0, acc0, 0, 0, 0);
                acc1 = __builtin_amdgcn_mfma_f32_32x32x16_bf16(a[s], b1, acc1, 0, 0, 0);
            }
        };

        short8 A0[NS], A1[NS];
        loadA(idx[0], A0);
        #pragma unroll 1
        for (int t = 0; t + 2 <= K; t += 2) {
            loadA(idx[t + 1], A1);          // prefetch next while doing cur
            dotap(t, idx[t], A0);
            if (t + 2 < K) loadA(idx[t + 2], A0);
            dotap(t + 1, idx[t + 1], A1);
        }
        dotap(K - 1, idx[K - 1], A0);       // K odd

        // epilogue: store bf16 + fused per-channel sum/sumsq
        float s0 = 0.f, q0 = 0.f, s1 = 0.f, q1 = 0.f;
        #pragma unroll
        for (int i = 0; i < 16; ++i) {
            int row = (i & 3) + 8 * (i >> 2) + 4 * q;
            int gr = rbase + row;
            if (gr < J.n_out) {
                float v0 = acc0[i], v1 = acc1[i];
                J.out[(size_t)gr * 64 + col] = __float2bfloat16(v0);
                J.out[(size_t)gr * 64 + 32 + col] = __float2bfloat16(v1);
                s0 += v0; q0 += v0 * v0;
                s1 += v1; q1 += v1 * v1;
            }
        }
        if (J.stat != nullptr) {
            s0 += __shfl_xor(s0, 32); q0 += __shfl_xor(q0, 32);
            s1 += __shfl_xor(s1, 32); q1 += __shfl_xor(q1, 32);
            float* st = J.stat + (((sb << 3) + widl) & 31) * 256;
            if (q == 0) {
                atomicAdd(&st[col], s0);
                atomicAdd(&st[64 + col], q0);
            } else {
                atomicAdd(&st[32 + col], s1);
                atomicAdd(&st[96 + col], q1);
            }
        }
    }
}

// ---------------- mpool_k: pool (K=27) with GROUP-STAGED LDS weights --------
// Round-6 counters: pool runs the old global-B path -> 342 vmem instr per
// tile-wave, 2/3 of them re-reading a 216KB L2-hot weight set; transaction-
// service bound at MfmaUtil 15%. 216KB > LDS, so stage taps in 3 groups of 9
// (72KB each): block-synchronous batches of 8 tiles (1/wave); per group,
// cooperative stage + barrier + mconv4-style dbuf tap loop; acc persists
// across groups. Vmem stream per tile-wave drops 342 -> ~140.
// Tail waves keep hitting barriers (loop bounds block-uniform, compute
// predicated) -- no divergent-barrier hazard.
template <int NS>  // NS = CIN/16 = 4
__global__ __launch_bounds__(512, 4) void mpool_k(
    const bf16* __restrict__ fin, const int* __restrict__ nbr,
    const bf16* __restrict__ Wp, bf16* __restrict__ out,
    int n_out, int n_in) {
    __shared__ short8 WL[9 * NS * 128];  // 72KB @ NS=4
    const int CIN = NS * 16;
    const int tid = threadIdx.x;
    const int lane = tid & 63;
    const int col = lane & 31;
    const int q = lane >> 5;
    const int widl = tid >> 6;  // 0..7

    // bijective chunked XCD swizzle
    const int nb = gridDim.x;
    const int qq = nb >> 3, rr = nb & 7;
    const int xcd = blockIdx.x & 7, bi = blockIdx.x >> 3;
    const int sb = (xcd < rr) ? xcd * (qq + 1) + bi
                              : rr * (qq + 1) + (xcd - rr) * qq + bi;

    const int ntiles = (n_out + 31) >> 5;
    const int nbatch = (ntiles + 7) >> 3;

    for (int batch = sb; batch < nbatch; batch += nb) {
        const int tile = (batch << 3) + widl;
        const int rbase = tile << 5;
        const int r = rbase + col;
        const bool rowok = (tile < ntiles) && (r < n_out);

        f32x16 acc0, acc1;
        #pragma unroll
        for (int i = 0; i < 16; ++i) { acc0[i] = 0.f; acc1[i] = 0.f; }

        auto loadA = [&](int id, short8 (&dst)[NS]) {
            const bool v = id < n_in;
            const bf16* src = fin + (size_t)id * CIN + q * 8;
            #pragma unroll
            for (int s = 0; s < NS; ++s) {
                short8 z = {0, 0, 0, 0, 0, 0, 0, 0};
                dst[s] = z;
                if (v) dst[s] = *(const short8*)(src + s * 16);
            }
        };
        auto dotap = [&](int k, int id, short8 (&a)[NS]) {
            if (__ballot(id < n_in) == 0ull) return;
            #pragma unroll
            for (int s = 0; s < NS; ++s) {
                short8 b0 = WL[((k * NS + s) * 2 + 0) * 64 + lane];
                short8 b1 = WL[((k * NS + s) * 2 + 1) * 64 + lane];
                acc0 = __builtin_amdgcn_mfma_f32_32x32x16_bf16(a[s], b0, acc0, 0, 0, 0);
                acc1 = __builtin_amdgcn_mfma_f32_32x32x16_bf16(a[s], b1, acc1, 0, 0, 0);
            }
        };

        #pragma unroll 1
        for (int g = 0; g < 3; ++g) {
            // stage taps 9g..9g+8 (72KB); barrier both sides
            __syncthreads();  // all waves done reading previous group
            {
                const short8* wsrc = (const short8*)Wp + (size_t)g * (9 * NS * 128);
                #pragma unroll
                for (int i = 0; i < (9 * NS * 128) / 512; ++i)
                    WL[i * 512 + tid] = wsrc[i * 512 + tid];
            }
            __syncthreads();  // staged weights visible

            int idx[9];
            #pragma unroll
            for (int t = 0; t < 9; ++t)
                idx[t] = rowok ? nbr[(size_t)(g * 9 + t) * n_out + r] : n_in;

            short8 A0[NS], A1[NS];
            loadA(idx[0], A0);
            #pragma unroll 1
            for (int t = 0; t + 2 <= 9; t += 2) {
                loadA(idx[t + 1], A1);
                dotap(t, idx[t], A0);
                if (t + 2 < 9) loadA(idx[t + 2], A0);
                dotap(t + 1, idx[t + 1], A1);
            }
            dotap(8, idx[8], A0);
        }

        #pragma unroll
        for (int i = 0; i < 16; ++i) {
            int row = (i & 3) + 8 * (i >> 2) + 4 * q;
            int gr = rbase + row;
            if (tile < ntiles && gr < n_out) {
                out[(size_t)gr * 64 + col] = __float2bfloat16(acc0[i]);
                out[(size_t)gr * 64 + 32 + col] = __float2bfloat16(acc1[i]);
            }
        }
    }
}

// ---------------- fused down-projection ----------------
__global__ __launch_bounds__(256, 6) void down_k(
    const bf16* __restrict__ x1, const bf16* __restrict__ x2,
    const bf16* __restrict__ x3, const bf16* __restrict__ W1,
    const bf16* __restrict__ W2, const bf16* __restrict__ W3,
    float* __restrict__ out, int m) {
    const int lane = threadIdx.x & 63;
    const int col = lane & 31;
    const int q = lane >> 5;
    const int wid = blockIdx.x * (blockDim.x >> 6) + (threadIdx.x >> 6);
    const int nw = gridDim.x * (blockDim.x >> 6);
    const int ntiles = (m + 31) >> 5;

    for (int tile = wid; tile < ntiles; tile += nw) {
        const int rbase = tile << 5;
        const int r = rbase + col;
        const bool rowok = r < m;

        f32x16 acc0, acc1;
        #pragma unroll
        for (int i = 0; i < 16; ++i) { acc0[i] = 0.f; acc1[i] = 0.f; }

        const bf16* xs[3] = {x1, x2, x3};
        const bf16* ws[3] = {W1, W2, W3};
        #pragma unroll 1
        for (int t = 0; t < 3; ++t) {
            const bf16* src = xs[t] + (size_t)r * 64 + q * 8;
            const short8* wp = (const short8*)ws[t] + lane;
            #pragma unroll
            for (int s = 0; s < 4; ++s) {
                short8 a;
                if (rowok) a = *(const short8*)(src + s * 16);
                else { short8 z = {0,0,0,0,0,0,0,0}; a = z; }
                short8 b0 = wp[(s * 2 + 0) * 64];
                short8 b1 = wp[(s * 2 + 1) * 64];
                acc0 = __builtin_amdgcn_mfma_f32_32x32x16_bf16(a, b0, acc0, 0, 0, 0);
                acc1 = __builtin_amdgcn_mfma_f32_32x32x16_bf16(a, b1, acc1, 0, 0, 0);
            }
        }
        #pragma unroll
        for (int i = 0; i < 16; ++i) {
            int row = (i & 3) + 8 * (i >> 2) + 4 * q;
            int gr = rbase + row;
            if (gr < m) {
                out[(size_t)gr * 64 + col] = acc0[i];
                out[(size_t)gr * 64 + 32 + col] = acc1[i];
            }
        }
    }
}

// ---------------- host ----------------

extern "C" void kernel_launch(void* const* d_in, const int* in_sizes, int n_in_,
                              void* d_out, int out_size, void* d_ws,
                              size_t ws_size, hipStream_t stream) {
    const float* feats = (const float*)d_in[0];
    const float* Wsrc[16] = {
        (const float*)d_in[1], (const float*)d_in[2],
        (const float*)d_in[3], (const float*)d_in[4],
        (const float*)d_in[5],
        (const float*)d_in[6], (const float*)d_in[7],
        (const float*)d_in[8], (const float*)d_in[9],
        (const float*)d_in[10], (const float*)d_in[11],
        (const float*)d_in[12], (const float*)d_in[13],
        (const float*)d_in[14],
        (const float*)d_in[14] + 64 * 64,
        (const float*)d_in[14] + 128 * 64,
    };
    const int kts[16] = {9,9,9,9, 27, 9,9,9,9, 9,9,9,9, 1,1,1};
    const int nss[16] = {2,4,2,4,  4, 4,4,4,4, 4,4,4,4, 4,4,4};

    const int* nA1 = (const int*)d_in[15];
    const int* nB1 = (const int*)d_in[16];
    const int* pnbr = (const int*)d_in[17];
    const int* nA2 = (const int*)d_in[18];
    const int* nB2 = (const int*)d_in[19];
    const int* nA3 = (const int*)d_in[20];
    const int* nB3 = (const int*)d_in[21];

    const int N = in_sizes[0] / 32;
    const int M = in_sizes[17] / 27;
    const size_t MX = (size_t)(N > M ? N : M);

    // ---- workspace ----
    bf16* A = (bf16*)d_ws;
    bf16* B = A + MX * 64;
    bf16* C = B + MX * 64;
    bf16* D = C + MX * 64;   // X1
    bf16* E = D + MX * 64;   // X2
    bf16* FB = E + MX * 64;  // feats bf16, N x 32
    bf16* WP = FB + (size_t)N * 32;
    bf16* G = (bf16*)d_out;  // bf16 scratch inside out (consumed before down_k)
    bf16* Wp[16];
    {
        size_t off = 0;
        for (int i = 0; i < 16; ++i) {
            Wp[i] = WP + off;
            off += (size_t)kts[i] * nss[i] * 1024;
        }
    }
    size_t wp_total = 0;
    for (int i = 0; i < 16; ++i) wp_total += (size_t)kts[i] * nss[i] * 1024;
    // 12 replicated stat slots (32 banks x 256 floats) + 12 finalized slots
    float* ST = (float*)(WP + wp_total + (wp_total & 1));
    float* FS = ST + (size_t)12 * 32 * 256;
    float* out = (float*)d_out;
    auto S = [&](int i) { return ST + (size_t)i * 32 * 256; };
    auto F = [&](int i) { return FS + (size_t)i * 128; };

    // ---- prep ----
    hipMemsetAsync(ST, 0, (size_t)12 * 32 * 256 * sizeof(float), stream);
    {
        PackArgs pa;
        for (int i = 0; i < 16; ++i) pa.e[i] = {Wsrc[i], Wp[i], kts[i], nss[i]};
        pack_w_k<<<dim3(64, 16), 256, 0, stream>>>(pa);
    }
    cvt_f32_bf16_k<<<(N * 32 + 255) / 256, 256, 0, stream>>>(feats, FB, N * 32);

    const float invN = 1.f / (float)N, invM = 1.f / (float)M;
    const int nvN = N * 8, nvM = M * 8;  // short8 vectors per tensor

    auto mkjob = [](const bf16* fin, const int* nbr, const bf16* w, bf16* o,
                    float* st, int no, int ni) {
        Job j; j.fin = fin; j.nbr = nbr; j.Wp = w; j.out = o; j.stat = st;
        j.n_out = no; j.n_in = ni; return j;
    };
    // paired 9-tap convs: one job per block, LDS weights, 512 thr, grid 512
    auto pair4 = [&](void (*kp)(Jobs4), Job a, Job b) {
        Jobs4 jb; jb.j[0] = a; jb.j[1] = b;
        const int nb = 512;
        long ta = (a.n_out + 31) >> 5, tb = (b.n_out + 31) >> 5;
        int bs = (int)((ta * nb + (ta + tb) / 2) / (ta + tb));
        if (bs < 1) bs = 1;
        if (bs > nb - 1) bs = nb - 1;
        jb.b_split = bs;
        hipLaunchKernelGGL(kp, dim3(nb), dim3(512), 0, stream, jb);
    };

    // ---- block 1 @ N, C 32->64 ----
    pair4(mconv4<2, 9>,
          mkjob(FB, nA1, Wp[0], A, S(0), N, N),
          mkjob(FB, nB1, Wp[2], B, S(2), N, N));
    finalize2_k<<<2, 64, 0, stream>>>(S(0), S(2), F(0), F(2), invN);
    bnact2_k<<<(2 * nvN + 255) / 256, 256, 0, stream>>>(A, F(0), B, F(2), nvN);
    pair4(mconv4<4, 9>,
          mkjob(A, nB1, Wp[1], C, S(1), N, N),
          mkjob(B, nA1, Wp[3], E, S(3), N, N));
    finalize2_k<<<2, 64, 0, stream>>>(S(1), S(3), F(1), F(3), invN);
    bnadd_k<<<(nvN + 255) / 256, 256, 0, stream>>>(C, F(1), E, F(3), B, nvN);
    // XP = B (N x 64)

    // ---- strided pool, K=27: B (N,64) -> D (M,64) = X1 ----
    mpool_k<4><<<512, 512, 0, stream>>>(B, pnbr, Wp[4], D, M, N);

    // ---- block 2 @ M (fin = D) ----
    pair4(mconv4<4, 9>,
          mkjob(D, nA2, Wp[5], A, S(4), M, M),
          mkjob(D, nB2, Wp[7], B, S(6), M, M));
    finalize2_k<<<2, 64, 0, stream>>>(S(4), S(6), F(4), F(6), invM);
    bnact2_k<<<(2 * nvM + 255) / 256, 256, 0, stream>>>(A, F(4), B, F(6), nvM);
    pair4(mconv4<4, 9>,
          mkjob(A, nB2, Wp[6], C, S(5), M, M),
          mkjob(B, nA2, Wp[8], E, S(7), M, M));
    finalize2_k<<<2, 64, 0, stream>>>(S(5), S(7), F(5), F(7), invM);
    bnadd_k<<<(nvM + 255) / 256, 256, 0, stream>>>(C, F(5), E, F(7), E, nvM);
    // X2 = E

    // ---- block 3 @ M (fin = E) ----
    pair4(mconv4<4, 9>,
          mkjob(E, nA3, Wp[9], A, S(8), M, M),
          mkjob(E, nB3, Wp[11], B, S(10), M, M));
    finalize2_k<<<2, 64, 0, stream>>>(S(8), S(10), F(8), F(10), invM);
    bnact2_k<<<(2 * nvM + 255) / 256, 256, 0, stream>>>(A, F(8), B, F(10), nvM);
    pair4(mconv4<4, 9>,
          mkjob(A, nB3, Wp[10], C, S(9), M, M),
          mkjob(B, nA3, Wp[12], G, S(11), M, M));
    finalize2_k<<<2, 64, 0, stream>>>(S(9), S(11), F(9), F(11), invM);
    bnadd_k<<<(nvM + 255) / 256, 256, 0, stream>>>(C, F(9), G, F(11), B, nvM);
    // X3 = B  (G scratch consumed)

    // ---- fused down: out = X1@W1 + X2@W2 + X3@W3 ----
    {
        int blocks = (((M + 31) >> 5) + 3) >> 2;
        down_k<<<blocks, 256, 0, stream>>>(D, E, B, Wp[13], Wp[14], Wp[15], out, M);
    }
}